// Round 1
// baseline (4346.215 us; speedup 1.0000x reference)
//
#include <hip/hip_runtime.h>

#define SEQ 999
#define HID 256
#define DTC 0.01f

typedef _Float16 h2 __attribute__((ext_vector_type(2)));

__device__ __forceinline__ h2 u2h(unsigned u){ return __builtin_bit_cast(h2, u); }
__device__ __forceinline__ unsigned h2u(h2 v){ return __builtin_bit_cast(unsigned, v); }

__device__ __forceinline__ float fdot2f(h2 a, h2 b, float c){
  return __builtin_amdgcn_fdot2(a, b, c, false);
}

__device__ __forceinline__ float softplusf(float x){
  return fmaxf(x, 0.f) + log1pf(__expf(-fabsf(x)));
}
__device__ __forceinline__ float sigmoidf(float x){
  return 1.f/(1.f + __expf(-x));
}
__device__ __forceinline__ float tanh_fast(float x){
  float e = __expf(-2.f*x);
  return (1.f - e)/(1.f + e);
}

// Convert recurrent/input weights to f16, TRANSPOSED: wT[c2*1024 + r] = (W[r][2c2], W[r][2c2+1])
// so both the layer-kernel prologue loads and the xw1 GEMM are lane-coalesced.
__global__ void k_convert(const float* __restrict__ whh0, const float* __restrict__ wih1,
                          const float* __restrict__ whh1,
                          const float* __restrict__ bih0, const float* __restrict__ bhh0,
                          const float* __restrict__ bih1, const float* __restrict__ bhh1,
                          h2* __restrict__ whh0T, h2* __restrict__ wih1T, h2* __restrict__ whh1T,
                          float* __restrict__ bs0, float* __restrict__ bs1){
  int o = blockIdx.x*256 + threadIdx.x;
  if (o < 131072){
    int r = o & 1023, c2 = o >> 10;
    const float* s = whh0 + r*256 + 2*c2;
    whh0T[o] = h2{(_Float16)s[0], (_Float16)s[1]};
  } else if (o < 262144){
    int oo = o - 131072; int r = oo & 1023, c2 = oo >> 10;
    const float* s = wih1 + r*256 + 2*c2;
    wih1T[oo] = h2{(_Float16)s[0], (_Float16)s[1]};
  } else if (o < 393216){
    int oo = o - 262144; int r = oo & 1023, c2 = oo >> 10;
    const float* s = whh1 + r*256 + 2*c2;
    whh1T[oo] = h2{(_Float16)s[0], (_Float16)s[1]};
  } else if (o < 394240){
    int r = o - 393216; bs0[r] = bih0[r] + bhh0[r];
  } else if (o < 395264){
    int r = o - 394240; bs1[r] = bih1[r] + bhh1[r];
  }
}

// One workgroup = one LSTM layer. 512 threads, thread owns rows (tid, tid+512).
// Weight row split: cols [0,192) in 96 half2 VGPRs, cols [192,256) in LDS (128 KB).
// h lives in LDS as half2[128]; broadcast b128 reads feed v_dot2_f32_f16.
template<int MODE>  // 0: layer0 (xw from Wih0 @ x_t), 1: layer1 (xw precomputed in xw1[])
__global__ __launch_bounds__(512, 2)
void k_layer(const h2* __restrict__ wT, const float* __restrict__ wih0,
             const float* __restrict__ bs, const float* __restrict__ X,
             const float* __restrict__ xw1, _Float16* __restrict__ hOutHalf,
             float* __restrict__ hOutF32){
  __shared__ uint2 wlds[2][16][512];               // 128 KB, lane stride 8B => conflict-free
  __shared__ __align__(16) h2 hlds[128];           // h_{t-1}, 512 B
  __shared__ float exch_i[256], exch_g[256];

  const int tid = threadIdx.x;
  const int r0 = tid, r1 = tid + 512;

  h2 w0[96], w1[96];
#pragma unroll
  for (int j=0;j<96;++j){ w0[j] = wT[j*1024 + r0]; w1[j] = wT[j*1024 + r1]; }
#pragma unroll
  for (int jj=0;jj<16;++jj){
    wlds[0][jj][tid] = make_uint2(h2u(wT[(96+2*jj)*1024 + r0]), h2u(wT[(97+2*jj)*1024 + r0]));
    wlds[1][jj][tid] = make_uint2(h2u(wT[(96+2*jj)*1024 + r1]), h2u(wT[(97+2*jj)*1024 + r1]));
  }

  float wiA0=0.f, wiA1=0.f, wiB0=0.f, wiB1=0.f, bsA=0.f, bsB=0.f;
  if (MODE == 0){
    wiA0 = wih0[2*r0]; wiA1 = wih0[2*r0+1];
    wiB0 = wih0[2*r1]; wiB1 = wih0[2*r1+1];
    bsA = bs[r0]; bsB = bs[r1];
  }
  if (tid < 128) hlds[tid] = h2{(_Float16)0.f, (_Float16)0.f};

  float c = 0.f;
  float nx0 = 0.f, nx1 = 0.f;
  if (MODE == 1){ nx0 = xw1[r0]; nx1 = xw1[r1]; }
  __syncthreads();

#pragma unroll 1
  for (int t=0; t<SEQ; ++t){
    float a0a, a1a;
    if (MODE == 0){
      float x0 = X[2*t], x1 = X[2*t+1];
      a0a = fmaf(wiA1, x1, fmaf(wiA0, x0, bsA));
      a1a = fmaf(wiB1, x1, fmaf(wiB0, x0, bsB));
    } else {
      a0a = nx0; a1a = nx1;
      if (t+1 < SEQ){ nx0 = xw1[(t+1)*1024 + r0]; nx1 = xw1[(t+1)*1024 + r1]; }  // prefetch
    }
    float a0b = 0.f, a1b = 0.f;
    const uint4* hv4 = (const uint4*)hlds;
#pragma unroll
    for (int q=0;q<24;++q){                        // register-resident weight part
      uint4 hv = hv4[q];
      h2 hA = u2h(hv.x), hB = u2h(hv.y), hC = u2h(hv.z), hD = u2h(hv.w);
      a0a = fdot2f(w0[4*q+0], hA, a0a);  a1a = fdot2f(w1[4*q+0], hA, a1a);
      a0b = fdot2f(w0[4*q+1], hB, a0b);  a1b = fdot2f(w1[4*q+1], hB, a1b);
      a0a = fdot2f(w0[4*q+2], hC, a0a);  a1a = fdot2f(w1[4*q+2], hC, a1a);
      a0b = fdot2f(w0[4*q+3], hD, a0b);  a1b = fdot2f(w1[4*q+3], hD, a1b);
    }
#pragma unroll
    for (int q=0;q<8;++q){                         // LDS-resident weight part
      uint4 hv = hv4[24+q];
      h2 hA = u2h(hv.x), hB = u2h(hv.y), hC = u2h(hv.z), hD = u2h(hv.w);
      uint2 u0a = wlds[0][2*q][tid],  u0b = wlds[0][2*q+1][tid];
      uint2 u1a = wlds[1][2*q][tid],  u1b = wlds[1][2*q+1][tid];
      a0a = fdot2f(u2h(u0a.x), hA, a0a);  a1a = fdot2f(u2h(u1a.x), hA, a1a);
      a0b = fdot2f(u2h(u0a.y), hB, a0b);  a1b = fdot2f(u2h(u1a.y), hB, a1b);
      a0a = fdot2f(u2h(u0b.x), hC, a0a);  a1a = fdot2f(u2h(u1b.x), hC, a1a);
      a0b = fdot2f(u2h(u0b.y), hD, a0b);  a1b = fdot2f(u2h(u1b.y), hD, a1b);
    }
    float a0 = a0a + a0b, a1 = a1a + a1b;

    // rows: [0,256)=i  [256,512)=f  [512,768)=g  [768,1024)=o
    float f_=0.f, o_=0.f;
    if (tid < 256){
      exch_i[tid] = sigmoidf(a0);    // i_k
      exch_g[tid] = tanh_fast(a1);   // g_k
    } else {
      f_ = sigmoidf(a0);             // f_k
      o_ = sigmoidf(a1);             // o_k
    }
    __syncthreads();
    if (tid >= 256){
      const int k = tid - 256;
      c = fmaf(f_, c, exch_i[k]*exch_g[k]);
      float h = o_ * tanh_fast(c);
      ((_Float16*)hlds)[k] = (_Float16)h;
      if (MODE == 0) hOutHalf[t*256 + k] = (_Float16)h;
      else           hOutF32 [t*256 + k] = h;
    }
    __syncthreads();
  }
}

// xw1[t][r] = bs1[r] + Wih1[r,:] . h0[t,:]  -- parallel over t, 8 t per block (weight reuse in L2)
__global__ __launch_bounds__(1024)
void k_xw1(const h2* __restrict__ wih1T, const float* __restrict__ bs1,
           const h2* __restrict__ h0, float* __restrict__ xw1){
  const int tid = threadIdx.x;
#pragma unroll 1
  for (int tt=0; tt<8; ++tt){
    int t = blockIdx.x*8 + tt;
    if (t >= SEQ) return;
    const uint4* hv4 = (const uint4*)(h0 + t*128);
    float acc = bs1[tid];
#pragma unroll
    for (int q=0;q<32;++q){
      uint4 hv = hv4[q];
      acc = fdot2f(wih1T[(4*q+0)*1024 + tid], u2h(hv.x), acc);
      acc = fdot2f(wih1T[(4*q+1)*1024 + tid], u2h(hv.y), acc);
      acc = fdot2f(wih1T[(4*q+2)*1024 + tid], u2h(hv.z), acc);
      acc = fdot2f(wih1T[(4*q+3)*1024 + tid], u2h(hv.w), acc);
    }
    xw1[t*1024 + tid] = acc;
  }
}

// z1[j] = softplus(W1[j,:] . h1_flat + b1[j]); one block per output row, 262 MB streamed once.
__global__ __launch_bounds__(256)
void k_w1(const float* __restrict__ W1, const float* __restrict__ b1,
          const float* __restrict__ h1f, float* __restrict__ z1){
  __shared__ float red[256];
  const int j = blockIdx.x, tid = threadIdx.x;
  const float4* w4 = (const float4*)(W1 + (size_t)j * (SEQ*HID));
  const float4* h4 = (const float4*)h1f;
  float acc = 0.f;
  for (int q = tid; q < (SEQ*HID/4); q += 256){
    float4 w = w4[q], h = h4[q];
    acc = fmaf(w.x, h.x, acc); acc = fmaf(w.y, h.y, acc);
    acc = fmaf(w.z, h.z, acc); acc = fmaf(w.w, h.w, acc);
  }
  red[tid] = acc; __syncthreads();
  for (int s=128; s>0; s>>=1){
    if (tid < s) red[tid] += red[tid+s];
    __syncthreads();
  }
  if (tid == 0) z1[j] = softplusf(red[0] + b1[j]);
}

// MLP tail + 999-step explicit Euler (serial, 1 thread)
__global__ __launch_bounds__(128)
void k_head(const float* __restrict__ W2, const float* __restrict__ b2,
            const float* __restrict__ W3, const float* __restrict__ b3,
            const float* __restrict__ z1, const float* __restrict__ data,
            float* __restrict__ out){
  __shared__ float z1s[256], z2s[128], ab[4];
  const int tid = threadIdx.x;
  z1s[tid] = z1[tid]; z1s[tid+128] = z1[tid+128];
  __syncthreads();
  float acc = b2[tid];
  for (int k=0;k<256;++k) acc = fmaf(W2[tid*256+k], z1s[k], acc);
  z2s[tid] = softplusf(acc);
  __syncthreads();
  if (tid < 4){
    float a = b3[tid];
    for (int k=0;k<128;++k) a = fmaf(W3[tid*128+k], z2s[k], a);
    ab[tid] = a;
  }
  __syncthreads();
  if (tid == 0){
    float a = ab[0], b = ab[1], cc = ab[2], d = ab[3];
    float R = data[0], J = data[1];
#pragma unroll 1
    for (int t=0;t<SEQ;++t){
      float RJ = R*J;
      float Rn = R + DTC*(a*R - b*RJ);
      float Jn = J + DTC*(d*RJ - cc*J);
      out[2*t] = Rn; out[2*t+1] = Jn;
      R = Rn; J = Jn;
    }
  }
}

extern "C" void kernel_launch(void* const* d_in, const int* in_sizes, int n_in,
                              void* d_out, int out_size, void* d_ws, size_t ws_size,
                              hipStream_t stream){
  const float* X    = (const float*)d_in[0];
  const float* data = (const float*)d_in[1];
  const float* Wih0 = (const float*)d_in[2];
  const float* Whh0 = (const float*)d_in[3];
  const float* bih0 = (const float*)d_in[4];
  const float* bhh0 = (const float*)d_in[5];
  const float* Wih1 = (const float*)d_in[6];
  const float* Whh1 = (const float*)d_in[7];
  const float* bih1 = (const float*)d_in[8];
  const float* bhh1 = (const float*)d_in[9];
  const float* W1   = (const float*)d_in[10];
  const float* b1   = (const float*)d_in[11];
  const float* W2   = (const float*)d_in[12];
  const float* b2   = (const float*)d_in[13];
  const float* W3   = (const float*)d_in[14];
  const float* b3   = (const float*)d_in[15];
  float* out = (float*)d_out;

  char* w = (char*)d_ws;
  h2*       whh0T = (h2*)(w + 0);              // 512 KB
  h2*       wih1T = (h2*)(w + 524288);         // 512 KB
  h2*       whh1T = (h2*)(w + 1048576);        // 512 KB
  float*    bs0   = (float*)(w + 1572864);     // 4 KB
  float*    bs1   = (float*)(w + 1576960);     // 4 KB
  _Float16* h0h   = (_Float16*)(w + 1581056);  // 999*256*2 = 511,488 B
  float*    xw1   = (float*)(w + 2097152);     // 999*1024*4 = 4,091,904 B
  float*    h1f   = (float*)(w + 6189056);     // 999*256*4 = 1,022,976 B
  float*    z1    = (float*)(w + 7212032);     // 1 KB   (total ~7.2 MB)

  k_convert<<<1544, 256, 0, stream>>>(Whh0, Wih1, Whh1, bih0, bhh0, bih1, bhh1,
                                      whh0T, wih1T, whh1T, bs0, bs1);
  k_layer<0><<<1, 512, 0, stream>>>(whh0T, Wih0, bs0, X, nullptr, h0h, nullptr);
  k_xw1<<<125, 1024, 0, stream>>>(wih1T, bs1, (const h2*)h0h, xw1);
  k_layer<1><<<1, 512, 0, stream>>>(whh1T, nullptr, bs1, nullptr, xw1, nullptr, h1f);
  k_w1<<<256, 256, 0, stream>>>(W1, b1, h1f, z1);
  k_head<<<1, 128, 0, stream>>>(W2, b2, W3, b3, z1, data, out);
}

// Round 2
// 4334.653 us; speedup vs baseline: 1.0027x; 1.0027x over previous
//
#include <hip/hip_runtime.h>

#define SEQ 999
#define HID 256
#define DTC 0.01f

typedef _Float16 h2 __attribute__((ext_vector_type(2)));

__device__ __forceinline__ h2 u2h(unsigned u){ return __builtin_bit_cast(h2, u); }
__device__ __forceinline__ unsigned h2u(h2 v){ return __builtin_bit_cast(unsigned, v); }

// v_dot2_f32_f16 with h in SGPR (src0), weight in VGPR (src1), acc tied src2/dst.
#define DOT(ACC, HS, WV) asm("v_dot2_f32_f16 %0, %1, %2, %0" : "+v"(ACC) : "s"(HS), "v"(WV))
// Pin a loaded value into a VGPR so the allocator cannot rematerialize the load in-loop.
#define PIN(V) asm volatile("" : "+v"(V))

__device__ __forceinline__ unsigned sel4(uint4 v, int k){
  return k==0 ? v.x : k==1 ? v.y : k==2 ? v.z : v.w;   // k is compile-time post-unroll
}

__device__ __forceinline__ float softplusf(float x){
  return fmaxf(x, 0.f) + log1pf(__expf(-fabsf(x)));
}
__device__ __forceinline__ float sigmoidf(float x){
  return 1.f/(1.f + __expf(-x));
}
__device__ __forceinline__ float tanh_fast(float x){
  float e = __expf(-2.f*x);
  return (1.f - e)/(1.f + e);
}

// Convert recurrent/input weights to f16, TRANSPOSED: wT[c2*1024 + r] = (W[r][2c2], W[r][2c2+1])
__global__ void k_convert(const float* __restrict__ whh0, const float* __restrict__ wih1,
                          const float* __restrict__ whh1,
                          const float* __restrict__ bih0, const float* __restrict__ bhh0,
                          const float* __restrict__ bih1, const float* __restrict__ bhh1,
                          h2* __restrict__ whh0T, h2* __restrict__ wih1T, h2* __restrict__ whh1T,
                          float* __restrict__ bs0, float* __restrict__ bs1){
  int o = blockIdx.x*256 + threadIdx.x;
  if (o < 131072){
    int r = o & 1023, c2 = o >> 10;
    const float* s = whh0 + r*256 + 2*c2;
    whh0T[o] = h2{(_Float16)s[0], (_Float16)s[1]};
  } else if (o < 262144){
    int oo = o - 131072; int r = oo & 1023, c2 = oo >> 10;
    const float* s = wih1 + r*256 + 2*c2;
    wih1T[oo] = h2{(_Float16)s[0], (_Float16)s[1]};
  } else if (o < 393216){
    int oo = o - 262144; int r = oo & 1023, c2 = oo >> 10;
    const float* s = whh1 + r*256 + 2*c2;
    whh1T[oo] = h2{(_Float16)s[0], (_Float16)s[1]};
  } else if (o < 394240){
    int r = o - 393216; bs0[r] = bih0[r] + bhh0[r];
  } else if (o < 395264){
    int r = o - 394240; bs1[r] = bih1[r] + bhh1[r];
  }
}

// One workgroup = one LSTM layer. 512 threads, thread owns rows (tid, tid+512).
// h(256 f16) gathered once per wave via one ds_read_b128 into lanes 0..31, then
// distributed by v_readlane into SGPRs feeding v_dot2_f32_f16 (SGPR src0).
// Weights: h2-cols [0,104) pinned in VGPRs (208/thread), cols [104,128) in LDS.
#define CREG 104          // h2-cols in registers per row
#define CLDS 12           // uint2 per row in LDS (24 h2-cols)

template<int MODE>  // 0: layer0 (xw from Wih0 @ x_t), 1: layer1 (xw precomputed in xw1[])
__global__ __launch_bounds__(512, 2)
void k_layer(const h2* __restrict__ wT, const float* __restrict__ wih0,
             const float* __restrict__ bs, const float* __restrict__ X,
             const float* __restrict__ xw1, _Float16* __restrict__ hOutHalf,
             float* __restrict__ hOutF32){
  __shared__ uint2 wlds[2][CLDS][512];             // 96 KB, lane stride 8B => 2-way (free)
  __shared__ __align__(16) h2 hlds[128];           // h_{t-1}, 512 B
  __shared__ float exch_i[256], exch_g[256];
  __shared__ float xlds[2*SEQ];                    // 8 KB (MODE 0 only)

  const int tid = threadIdx.x;
  const int r0 = tid, r1 = tid + 512;

  unsigned w0[CREG], w1[CREG];
#pragma unroll
  for (int j=0;j<CREG;++j){
    w0[j] = h2u(wT[j*1024 + r0]);
    w1[j] = h2u(wT[j*1024 + r1]);
  }
#pragma unroll
  for (int j=0;j<CREG;++j){ PIN(w0[j]); PIN(w1[j]); }
#pragma unroll
  for (int jj=0;jj<CLDS;++jj){
    wlds[0][jj][tid] = make_uint2(h2u(wT[(CREG+2*jj)*1024 + r0]), h2u(wT[(CREG+2*jj+1)*1024 + r0]));
    wlds[1][jj][tid] = make_uint2(h2u(wT[(CREG+2*jj)*1024 + r1]), h2u(wT[(CREG+2*jj+1)*1024 + r1]));
  }

  float wiA0=0.f, wiA1=0.f, wiB0=0.f, wiB1=0.f, bsA=0.f, bsB=0.f;
  if (MODE == 0){
    wiA0 = wih0[2*r0]; wiA1 = wih0[2*r0+1];
    wiB0 = wih0[2*r1]; wiB1 = wih0[2*r1+1];
    bsA = bs[r0]; bsB = bs[r1];
    for (int i=tid; i<2*SEQ; i+=512) xlds[i] = X[i];
  }
  if (tid < 128) hlds[tid] = h2{(_Float16)0.f, (_Float16)0.f};

  float c = 0.f;
  float nx0 = 0.f, nx1 = 0.f;
  if (MODE == 1){ nx0 = xw1[r0]; nx1 = xw1[r1]; }
  __syncthreads();

  uint4 hv = *(const uint4*)((const char*)hlds + (tid&31)*16);   // h gather (zeros)

#pragma unroll 1
  for (int t=0; t<SEQ; ++t){
    float a0, a1;
    if (MODE == 0){
      float2 xv = *(const float2*)&xlds[2*t];
      a0 = fmaf(wiA1, xv.y, fmaf(wiA0, xv.x, bsA));
      a1 = fmaf(wiB1, xv.y, fmaf(wiB0, xv.x, bsB));
    } else {
      a0 = nx0; a1 = nx1;
      if (t+1 < SEQ){ nx0 = xw1[(t+1)*1024 + r0]; nx1 = xw1[(t+1)*1024 + r1]; }  // prefetch
    }
    float a0b = 0.f, a1b = 0.f;

    // Register-resident weight part: readlane h2[j] -> SGPR, two dots per j.
#pragma unroll
    for (int j=0;j<CREG;++j){
      unsigned hh = (unsigned)__builtin_amdgcn_readlane((int)sel4(hv, j&3), j>>2);
      if (j & 1){ DOT(a0b, hh, w0[j]); DOT(a1b, hh, w1[j]); }
      else      { DOT(a0,  hh, w0[j]); DOT(a1,  hh, w1[j]); }
    }
    // LDS-resident weight part (cols CREG..127).
#pragma unroll
    for (int jj=0;jj<CLDS;++jj){
      uint2 u0 = wlds[0][jj][tid], u1 = wlds[1][jj][tid];
      const int ja = CREG + 2*jj, jb = CREG + 2*jj + 1;
      unsigned ha = (unsigned)__builtin_amdgcn_readlane((int)sel4(hv, ja&3), ja>>2);
      unsigned hb = (unsigned)__builtin_amdgcn_readlane((int)sel4(hv, jb&3), jb>>2);
      DOT(a0,  ha, u0.x); DOT(a1,  ha, u1.x);
      DOT(a0b, hb, u0.y); DOT(a1b, hb, u1.y);
    }
    a0 += a0b; a1 += a1b;

    // rows: [0,256)=i  [256,512)=f  [512,768)=g  [768,1024)=o
    float f_=0.f, o_=0.f;
    if (tid < 256){
      exch_i[tid] = sigmoidf(a0);    // i_k
      exch_g[tid] = tanh_fast(a1);   // g_k
    } else {
      f_ = sigmoidf(a0);             // f_k
      o_ = sigmoidf(a1);             // o_k
    }
    __syncthreads();
    if (tid >= 256){
      const int k = tid - 256;
      c = fmaf(f_, c, exch_i[k]*exch_g[k]);
      float h = o_ * tanh_fast(c);
      ((_Float16*)hlds)[k] = (_Float16)h;
      if (MODE == 0) hOutHalf[t*256 + k] = (_Float16)h;
      else           hOutF32 [t*256 + k] = h;
    }
    __syncthreads();
    hv = *(const uint4*)((const char*)hlds + (tid&31)*16);       // gather new h
  }
}

// xw1[t][r] = bs1[r] + Wih1[r,:] . h0[t,:]  -- parallel over t
__global__ __launch_bounds__(1024)
void k_xw1(const h2* __restrict__ wih1T, const float* __restrict__ bs1,
           const h2* __restrict__ h0, float* __restrict__ xw1){
  const int tid = threadIdx.x;
#pragma unroll 1
  for (int tt=0; tt<8; ++tt){
    int t = blockIdx.x*8 + tt;
    if (t >= SEQ) return;
    const uint4* hv4 = (const uint4*)(h0 + t*128);
    float acc = bs1[tid];
#pragma unroll
    for (int q=0;q<32;++q){
      uint4 hv = hv4[q];
      acc = __builtin_amdgcn_fdot2(u2h(hv.x), u2h(h2u(wih1T[(4*q+0)*1024 + tid])), acc, false);
      acc = __builtin_amdgcn_fdot2(u2h(hv.y), u2h(h2u(wih1T[(4*q+1)*1024 + tid])), acc, false);
      acc = __builtin_amdgcn_fdot2(u2h(hv.z), u2h(h2u(wih1T[(4*q+2)*1024 + tid])), acc, false);
      acc = __builtin_amdgcn_fdot2(u2h(hv.w), u2h(h2u(wih1T[(4*q+3)*1024 + tid])), acc, false);
    }
    xw1[t*1024 + tid] = acc;
  }
}

// z1[j] = softplus(W1[j,:] . h1_flat + b1[j]); one block per output row, 262 MB streamed once.
__global__ __launch_bounds__(256)
void k_w1(const float* __restrict__ W1, const float* __restrict__ b1,
          const float* __restrict__ h1f, float* __restrict__ z1){
  __shared__ float red[256];
  const int j = blockIdx.x, tid = threadIdx.x;
  const float4* w4 = (const float4*)(W1 + (size_t)j * (SEQ*HID));
  const float4* h4 = (const float4*)h1f;
  float acc = 0.f;
  for (int q = tid; q < (SEQ*HID/4); q += 256){
    float4 w = w4[q], h = h4[q];
    acc = fmaf(w.x, h.x, acc); acc = fmaf(w.y, h.y, acc);
    acc = fmaf(w.z, h.z, acc); acc = fmaf(w.w, h.w, acc);
  }
  red[tid] = acc; __syncthreads();
  for (int s=128; s>0; s>>=1){
    if (tid < s) red[tid] += red[tid+s];
    __syncthreads();
  }
  if (tid == 0) z1[j] = softplusf(red[0] + b1[j]);
}

// MLP tail + 999-step explicit Euler (serial, 1 thread)
__global__ __launch_bounds__(128)
void k_head(const float* __restrict__ W2, const float* __restrict__ b2,
            const float* __restrict__ W3, const float* __restrict__ b3,
            const float* __restrict__ z1, const float* __restrict__ data,
            float* __restrict__ out){
  __shared__ float z1s[256], z2s[128], ab[4];
  const int tid = threadIdx.x;
  z1s[tid] = z1[tid]; z1s[tid+128] = z1[tid+128];
  __syncthreads();
  float acc = b2[tid];
  for (int k=0;k<256;++k) acc = fmaf(W2[tid*256+k], z1s[k], acc);
  z2s[tid] = softplusf(acc);
  __syncthreads();
  if (tid < 4){
    float a = b3[tid];
    for (int k=0;k<128;++k) a = fmaf(W3[tid*128+k], z2s[k], a);
    ab[tid] = a;
  }
  __syncthreads();
  if (tid == 0){
    float a = ab[0], b = ab[1], cc = ab[2], d = ab[3];
    float R = data[0], J = data[1];
#pragma unroll 1
    for (int t=0;t<SEQ;++t){
      float RJ = R*J;
      float Rn = R + DTC*(a*R - b*RJ);
      float Jn = J + DTC*(d*RJ - cc*J);
      out[2*t] = Rn; out[2*t+1] = Jn;
      R = Rn; J = Jn;
    }
  }
}

extern "C" void kernel_launch(void* const* d_in, const int* in_sizes, int n_in,
                              void* d_out, int out_size, void* d_ws, size_t ws_size,
                              hipStream_t stream){
  const float* X    = (const float*)d_in[0];
  const float* data = (const float*)d_in[1];
  const float* Wih0 = (const float*)d_in[2];
  const float* Whh0 = (const float*)d_in[3];
  const float* bih0 = (const float*)d_in[4];
  const float* bhh0 = (const float*)d_in[5];
  const float* Wih1 = (const float*)d_in[6];
  const float* Whh1 = (const float*)d_in[7];
  const float* bih1 = (const float*)d_in[8];
  const float* bhh1 = (const float*)d_in[9];
  const float* W1   = (const float*)d_in[10];
  const float* b1   = (const float*)d_in[11];
  const float* W2   = (const float*)d_in[12];
  const float* b2   = (const float*)d_in[13];
  const float* W3   = (const float*)d_in[14];
  const float* b3   = (const float*)d_in[15];
  float* out = (float*)d_out;

  char* w = (char*)d_ws;
  h2*       whh0T = (h2*)(w + 0);              // 512 KB
  h2*       wih1T = (h2*)(w + 524288);         // 512 KB
  h2*       whh1T = (h2*)(w + 1048576);        // 512 KB
  float*    bs0   = (float*)(w + 1572864);     // 4 KB
  float*    bs1   = (float*)(w + 1576960);     // 4 KB
  _Float16* h0h   = (_Float16*)(w + 1581056);  // 999*256*2 = 511,488 B
  float*    xw1   = (float*)(w + 2097152);     // 999*1024*4 = 4,091,904 B
  float*    h1f   = (float*)(w + 6189056);     // 999*256*4 = 1,022,976 B
  float*    z1    = (float*)(w + 7212032);     // 1 KB   (total ~7.2 MB)

  k_convert<<<1544, 256, 0, stream>>>(Whh0, Wih1, Whh1, bih0, bhh0, bih1, bhh1,
                                      whh0T, wih1T, whh1T, bs0, bs1);
  k_layer<0><<<1, 512, 0, stream>>>(whh0T, Wih0, bs0, X, nullptr, h0h, nullptr);
  k_xw1<<<125, 1024, 0, stream>>>(wih1T, bs1, (const h2*)h0h, xw1);
  k_layer<1><<<1, 512, 0, stream>>>(whh1T, nullptr, bs1, nullptr, xw1, nullptr, h1f);
  k_w1<<<256, 256, 0, stream>>>(W1, b1, h1f, z1);
  k_head<<<1, 128, 0, stream>>>(W2, b2, W3, b3, z1, data, out);
}